// Round 3
// baseline (457.281 us; speedup 1.0000x reference)
//
#include <hip/hip_runtime.h>
#include <hip/hip_bf16.h>
#include <cstdint>
#include <cstddef>

typedef unsigned short u16;
typedef __bf16 bf16x8 __attribute__((ext_vector_type(8)));
typedef float  f32x4  __attribute__((ext_vector_type(4)));
typedef u16    u16x8  __attribute__((ext_vector_type(8)));
typedef u16    u16x4  __attribute__((ext_vector_type(4)));

#define MFMA16(A_, B_, C_) __builtin_amdgcn_mfma_f32_16x16x32_bf16((A_), (B_), (C_), 0, 0, 0)

__device__ __forceinline__ u16 f2bf(float f) {
  return __builtin_bit_cast(u16, (__bf16)f);
}
__device__ __forceinline__ float bf2f(u16 v) {
  return (float)__builtin_bit_cast(__bf16, v);
}

// async global->LDS, 16B per lane. lds must be wave-uniform base; HW adds lane*16.
__device__ __forceinline__ void async16(u16* lds, const u16* g) {
  __builtin_amdgcn_global_load_lds(
      (const __attribute__((address_space(1))) unsigned int*)g,
      (__attribute__((address_space(3))) unsigned int*)lds, 16, 0, 0);
}

// ---------------- prep kernels ----------------

__global__ void cvt_f32_bf16(const float* __restrict__ src, u16* __restrict__ dst, int n4) {
  int i = blockIdx.x * 256 + threadIdx.x;
  if (i < n4) {
    const float4 v = ((const float4*)src)[i];
    u16x4 o;
    o[0] = f2bf(v.x); o[1] = f2bf(v.y); o[2] = f2bf(v.z); o[3] = f2bf(v.w);
    ((u16x4*)dst)[i] = o;
  }
}

__global__ void bn_prep(const float* __restrict__ g, const float* __restrict__ b,
                        const float* __restrict__ rm, const float* __restrict__ rv,
                        float* __restrict__ alpha, float* __restrict__ beta,
                        int n, float scale) {
  int i = blockIdx.x * 256 + threadIdx.x;
  if (i < n) {
    float a0 = g[i] * rsqrtf(rv[i] + 1e-5f);
    alpha[i] = a0 * scale;
    beta[i]  = (b[i] - rm[i] * a0) * scale;
  }
}

__global__ void bias_expand_bf16(const float* __restrict__ attn_bias, const int* __restrict__ idxs,
                                 u16* __restrict__ bias_bf, int n_off) {
  int i = blockIdx.x * 256 + threadIdx.x;
  if (i < 8 * 320 * 1280) {
    int h = i / (320 * 1280);
    int r = i - h * (320 * 1280);
    bias_bf[i] = f2bf(attn_bias[h * n_off + idxs[r]]);
  }
}

// ---------------- GEMM 1: kv = x @ W_kv^T, BN, scatter to K / V^T ----------------
// 128x128 tile, BK=64, 4 waves. Linear LDS [128][64] + global_load_lds width-16.

__global__ __launch_bounds__(256) void gemm_kv(
    const u16* __restrict__ A, const u16* __restrict__ Wt,
    const float* __restrict__ alpha, const float* __restrict__ beta,
    u16* __restrict__ k_buf, u16* __restrict__ vt_buf) {
  __shared__ __align__(16) u16 As[128 * 64];
  __shared__ __align__(16) u16 Bs[128 * 64];
  const int tid  = threadIdx.x;
  const int lane = tid & 63;
  const int w    = tid >> 6;
  const int wr   = (w >> 1) * 64, wc = (w & 1) * 64;
  const int lr   = lane >> 4, lc = lane & 15;
  const int m0   = blockIdx.x * 128;
  const int n0   = blockIdx.y * 128;
  const int srow8 = lane >> 3;
  const int scol  = (lane & 7) * 8;
  f32x4 acc[4][4] = {};

  for (int kt = 0; kt < 256; kt += 64) {
    if (kt) __syncthreads();
#pragma unroll
    for (int i = 0; i < 4; ++i) {
      const int row = w * 32 + i * 8 + srow8;
      async16(&As[(w * 32 + i * 8) * 64], A  + (size_t)(m0 + row) * 256 + kt + scol);
      async16(&Bs[(w * 32 + i * 8) * 64], Wt + (size_t)(n0 + row) * 256 + kt + scol);
    }
    __syncthreads();
#pragma unroll
    for (int kk = 0; kk < 2; ++kk) {
      bf16x8 af[4], bff[4];
#pragma unroll
      for (int m = 0; m < 4; ++m)
        af[m] = *(const bf16x8*)(&As[(wr + m * 16 + lc) * 64 + kk * 32 + lr * 8]);
#pragma unroll
      for (int n = 0; n < 4; ++n)
        bff[n] = *(const bf16x8*)(&Bs[(wc + n * 16 + lc) * 64 + kk * 32 + lr * 8]);
#pragma unroll
      for (int m = 0; m < 4; ++m)
#pragma unroll
        for (int n = 0; n < 4; ++n)
          acc[m][n] = MFMA16(af[m], bff[n], acc[m][n]);
    }
  }

  const int jr = lr * 4;
#pragma unroll
  for (int m = 0; m < 4; ++m) {
    const int r0  = m0 + wr + m * 16 + jr;
    const int b   = r0 / 1280;
    const int np0 = r0 - b * 1280;
#pragma unroll
    for (int n = 0; n < 4; ++n) {
      const int c    = n0 + wc + n * 16 + lc;
      const float al = alpha[c], be = beta[c];
      const int head = c / 192;
      const int off  = c - head * 192;
      const size_t bh = (size_t)(b * 8 + head);
      if (off < 64) {
#pragma unroll
        for (int j = 0; j < 4; ++j)
          k_buf[(bh * 1280 + np0 + j) * 64 + off] = f2bf(acc[m][n][j] * al + be);
      } else {
        u16x4 pk;
#pragma unroll
        for (int j = 0; j < 4; ++j) pk[j] = f2bf(acc[m][n][j] * al + be);
        *(u16x4*)(&vt_buf[(bh * 128 + (off - 64)) * 1280 + np0]) = pk;
      }
    }
  }
}

// ---------------- GEMM 2: q = subsample(x) @ W_q^T, BN, *0.125 (folded) ----------------

__device__ __forceinline__ int sub_src_row(int qr) {
  if (qr < 256) return ((qr >> 4) * 64) + ((qr & 15) * 2);
  int rr = qr - 256;
  return 1024 + ((rr >> 3) * 32) + ((rr & 7) * 2);
}

__global__ __launch_bounds__(256) void gemm_q(
    const u16* __restrict__ X, const u16* __restrict__ Wt,
    const float* __restrict__ alpha, const float* __restrict__ beta,
    u16* __restrict__ q_buf) {
  __shared__ __align__(16) u16 As[128 * 64];
  __shared__ __align__(16) u16 Bs[128 * 64];
  const int tid  = threadIdx.x;
  const int lane = tid & 63;
  const int w    = tid >> 6;
  const int wr   = (w >> 1) * 64, wc = (w & 1) * 64;
  const int lr   = lane >> 4, lc = lane & 15;
  const int m0   = blockIdx.x * 128;
  const int n0   = blockIdx.y * 128;
  const int srow8 = lane >> 3;
  const int scol  = (lane & 7) * 8;
  f32x4 acc[4][4] = {};

  for (int kt = 0; kt < 256; kt += 64) {
    if (kt) __syncthreads();
#pragma unroll
    for (int i = 0; i < 4; ++i) {
      const int row = w * 32 + i * 8 + srow8;
      const int gr  = m0 + row;
      const int bb  = gr / 320;
      const int qr  = gr - bb * 320;
      async16(&As[(w * 32 + i * 8) * 64],
              X + (size_t)(bb * 1280 + sub_src_row(qr)) * 256 + kt + scol);
      async16(&Bs[(w * 32 + i * 8) * 64], Wt + (size_t)(n0 + row) * 256 + kt + scol);
    }
    __syncthreads();
#pragma unroll
    for (int kk = 0; kk < 2; ++kk) {
      bf16x8 af[4], bff[4];
#pragma unroll
      for (int m = 0; m < 4; ++m)
        af[m] = *(const bf16x8*)(&As[(wr + m * 16 + lc) * 64 + kk * 32 + lr * 8]);
#pragma unroll
      for (int n = 0; n < 4; ++n)
        bff[n] = *(const bf16x8*)(&Bs[(wc + n * 16 + lc) * 64 + kk * 32 + lr * 8]);
#pragma unroll
      for (int m = 0; m < 4; ++m)
#pragma unroll
        for (int n = 0; n < 4; ++n)
          acc[m][n] = MFMA16(af[m], bff[n], acc[m][n]);
    }
  }

  const int jr = lr * 4;
#pragma unroll
  for (int m = 0; m < 4; ++m) {
#pragma unroll
    for (int n = 0; n < 4; ++n) {
      const int c    = n0 + wc + n * 16 + lc;   // < 512
      const float al = alpha[c], be = beta[c];
      const int head = c >> 6, kd = c & 63;
#pragma unroll
      for (int j = 0; j < 4; ++j) {
        const int r  = m0 + wr + m * 16 + jr + j;
        const int b  = r / 320;
        const int qr = r - b * 320;
        q_buf[((size_t)(b * 8 + head) * 320 + qr) * 64 + kd] = f2bf(acc[m][n][j] * al + be);
      }
    }
  }
}

// ---------------- attention ----------------
// 1 block = 64 q-rows (4 waves x 16). NO K/V LDS staging (L2/L3-resident; m169),
// NO barriers: waves fully independent. P round-trip via per-wave LDS (lgkmcnt only).
// Defer-max (THR=8): fast path has zero shuffles. Row-sum via all-ones MFMA column.

__global__ __launch_bounds__(256) void attn_kernel(
    const u16* __restrict__ q_buf, const u16* __restrict__ k_buf,
    const u16* __restrict__ vt_buf, const u16* __restrict__ bias_bf,
    u16* __restrict__ o_buf) {
  __shared__ __align__(16) u16 Ps[4 * 16 * 72];
  const int tid  = threadIdx.x;
  const int lane = tid & 63;
  const int w    = tid >> 6;
  const int lr   = lane >> 4, lc = lane & 15, jr = lr * 4;
  const int h = blockIdx.y, b = blockIdx.z;
  const size_t bh = (size_t)(b * 8 + h);
  const int q0 = blockIdx.x * 64 + w * 16;

  bf16x8 aq0, aq1;
  {
    const u16* qp = q_buf + (bh * 320 + q0 + lc) * 64 + lr * 8;
    aq0 = *(const bf16x8*)(qp);
    aq1 = *(const bf16x8*)(qp + 32);
  }
  bf16x8 ones;
#pragma unroll
  for (int i = 0; i < 8; ++i) ones[i] = (__bf16)1.0f;

  f32x4 oacc[8] = {};
  f32x4 lacc = {};
  float mrun[4] = {-3e38f, -3e38f, -3e38f, -3e38f};

  u16* Pw = &Ps[w * 16 * 72];
  const u16* bias_row = bias_bf + ((size_t)h * 320 + q0 + jr) * 1280;
  const u16* kbase = k_buf + bh * 1280 * 64 + (size_t)lc * 64 + lr * 8;      // + row*64
  const u16* vbase = vt_buf + bh * 128 * 1280 + (size_t)lc * 1280 + lr * 8;  // + d*1280 + k0

  for (int kt = 0; kt < 20; ++kt) {
    const int k0 = kt * 64;

    // S = Q K^T (rows=q, cols=keys), K fragments straight from global (L2-hot)
    float pv[4][4];
    float mxl[4];
    __builtin_amdgcn_s_setprio(1);
#pragma unroll
    for (int n = 0; n < 4; ++n) {
      const u16* kp = kbase + (size_t)(k0 + n * 16) * 64;
      f32x4 t = {};
      t = MFMA16(aq0, *(const bf16x8*)(kp), t);
      t = MFMA16(aq1, *(const bf16x8*)(kp + 32), t);
#pragma unroll
      for (int j = 0; j < 4; ++j) pv[n][j] = t[j];
    }
    __builtin_amdgcn_s_setprio(0);

#pragma unroll
    for (int j = 0; j < 4; ++j) {
      const u16* bp = bias_row + (size_t)j * 1280 + k0 + lc;
      float v0 = pv[0][j] + bf2f(bp[0]);
      float v1 = pv[1][j] + bf2f(bp[16]);
      float v2 = pv[2][j] + bf2f(bp[32]);
      float v3 = pv[3][j] + bf2f(bp[48]);
      pv[0][j] = v0; pv[1][j] = v1; pv[2][j] = v2; pv[3][j] = v3;
      mxl[j] = fmaxf(fmaxf(v0, v1), fmaxf(v2, v3));
    }

    int cond = 1;
#pragma unroll
    for (int j = 0; j < 4; ++j) cond &= (mxl[j] <= mrun[j] + 8.f);
    if (!__all(cond)) {
#pragma unroll
      for (int j = 0; j < 4; ++j) {
        float v = mxl[j];
        v = fmaxf(v, __shfl_xor(v, 1));
        v = fmaxf(v, __shfl_xor(v, 2));
        v = fmaxf(v, __shfl_xor(v, 4));
        v = fmaxf(v, __shfl_xor(v, 8));
        const float mnew = fmaxf(mrun[j], v);
        const float corr = __expf(mrun[j] - mnew);
        mrun[j] = mnew;
        lacc[j] *= corr;
#pragma unroll
        for (int nc = 0; nc < 8; ++nc) oacc[nc][j] *= corr;
      }
    }

#pragma unroll
    for (int n = 0; n < 4; ++n)
#pragma unroll
      for (int j = 0; j < 4; ++j)
        Pw[(jr + j) * 72 + n * 16 + lc] = f2bf(__expf(pv[n][j] - mrun[j]));
    asm volatile("" ::: "memory");  // order u16 LDS stores vs bf16x8 loads (TBAA guard)

    bf16x8 pa0 = *(const bf16x8*)(&Pw[lc * 72 + lr * 8]);
    bf16x8 pa1 = *(const bf16x8*)(&Pw[lc * 72 + 32 + lr * 8]);
    __builtin_amdgcn_s_setprio(1);
    lacc = MFMA16(pa0, ones, lacc);  // row-sum: every lane gets l[row]
    lacc = MFMA16(pa1, ones, lacc);
#pragma unroll
    for (int nc = 0; nc < 8; ++nc) {
      const u16* vp = vbase + (size_t)(nc * 16) * 1280 + k0;
      oacc[nc] = MFMA16(pa0, *(const bf16x8*)(vp), oacc[nc]);
      oacc[nc] = MFMA16(pa1, *(const bf16x8*)(vp + 32), oacc[nc]);
    }
    __builtin_amdgcn_s_setprio(0);
  }

  float invl[4];
#pragma unroll
  for (int j = 0; j < 4; ++j) invl[j] = 1.f / lacc[j];
#pragma unroll
  for (int nc = 0; nc < 8; ++nc) {
#pragma unroll
    for (int j = 0; j < 4; ++j) {
      const float xv = oacc[nc][j] * invl[j];
      const float hs = xv * fminf(fmaxf(xv + 3.f, 0.f), 6.f) * (1.f / 6.f);
      o_buf[((size_t)b * 320 + q0 + jr + j) * 1024 + h * 128 + nc * 16 + lc] = f2bf(hs);
    }
  }
}

// ---------------- GEMM 3: out = hswish(o) @ W_p^T, BN (f32 out) ----------------

__global__ __launch_bounds__(256) void gemm_p(
    const u16* __restrict__ O, const u16* __restrict__ Wt,
    const float* __restrict__ alpha, const float* __restrict__ beta,
    float* __restrict__ out) {
  __shared__ __align__(16) u16 As[128 * 64];
  __shared__ __align__(16) u16 Bs[128 * 64];
  const int tid  = threadIdx.x;
  const int lane = tid & 63;
  const int w    = tid >> 6;
  const int wr   = (w >> 1) * 64, wc = (w & 1) * 64;
  const int lr   = lane >> 4, lc = lane & 15;
  const int m0   = blockIdx.x * 128;
  const int n0   = blockIdx.y * 128;
  const int srow8 = lane >> 3;
  const int scol  = (lane & 7) * 8;
  f32x4 acc[4][4] = {};

  for (int kt = 0; kt < 1024; kt += 64) {
    if (kt) __syncthreads();
#pragma unroll
    for (int i = 0; i < 4; ++i) {
      const int row = w * 32 + i * 8 + srow8;
      async16(&As[(w * 32 + i * 8) * 64], O  + (size_t)(m0 + row) * 1024 + kt + scol);
      async16(&Bs[(w * 32 + i * 8) * 64], Wt + (size_t)(n0 + row) * 1024 + kt + scol);
    }
    __syncthreads();
#pragma unroll
    for (int kk = 0; kk < 2; ++kk) {
      bf16x8 af[4], bff[4];
#pragma unroll
      for (int m = 0; m < 4; ++m)
        af[m] = *(const bf16x8*)(&As[(wr + m * 16 + lc) * 64 + kk * 32 + lr * 8]);
#pragma unroll
      for (int n = 0; n < 4; ++n)
        bff[n] = *(const bf16x8*)(&Bs[(wc + n * 16 + lc) * 64 + kk * 32 + lr * 8]);
#pragma unroll
      for (int m = 0; m < 4; ++m)
#pragma unroll
        for (int n = 0; n < 4; ++n)
          acc[m][n] = MFMA16(af[m], bff[n], acc[m][n]);
    }
  }

  const int jr = lr * 4;
#pragma unroll
  for (int m = 0; m < 4; ++m) {
#pragma unroll
    for (int n = 0; n < 4; ++n) {
      const int c = n0 + wc + n * 16 + lc;   // < 384
      const float al = alpha[c], be = beta[c];
#pragma unroll
      for (int j = 0; j < 4; ++j) {
        const int r = m0 + wr + m * 16 + jr + j;
        out[(size_t)r * 384 + c] = acc[m][n][j] * al + be;
      }
    }
  }
}

// ---------------- launch ----------------

extern "C" void kernel_launch(void* const* d_in, const int* in_sizes, int n_in,
                              void* d_out, int out_size, void* d_ws, size_t ws_size,
                              hipStream_t stream) {
  const float* x      = (const float*)d_in[0];
  const float* W_kv   = (const float*)d_in[1];
  const float* g_kv   = (const float*)d_in[2];
  const float* b_kv   = (const float*)d_in[3];
  const float* rm_kv  = (const float*)d_in[4];
  const float* rv_kv  = (const float*)d_in[5];
  const float* W_q    = (const float*)d_in[6];
  const float* g_q    = (const float*)d_in[7];
  const float* b_q    = (const float*)d_in[8];
  const float* rm_q   = (const float*)d_in[9];
  const float* rv_q   = (const float*)d_in[10];
  const float* W_p    = (const float*)d_in[11];
  const float* g_p    = (const float*)d_in[12];
  const float* b_p    = (const float*)d_in[13];
  const float* rm_p   = (const float*)d_in[14];
  const float* rv_p   = (const float*)d_in[15];
  const float* attn_bias = (const float*)d_in[16];
  const int*   bias_idxs = (const int*)d_in[17];
  const int n_off = in_sizes[16] / 8;

  char* ws = (char*)d_ws;
  size_t off = 0;
  auto alloc = [&](size_t bytes) -> void* {
    void* p = ws + off;
    off += (bytes + 255) & ~(size_t)255;
    return p;
  };
  u16* x_bf    = (u16*)alloc((size_t)40960 * 256 * 2);
  u16* wkv_bf  = (u16*)alloc((size_t)1536 * 256 * 2);
  u16* wq_bf   = (u16*)alloc((size_t)512 * 256 * 2);
  u16* wp_bf   = (u16*)alloc((size_t)384 * 1024 * 2);
  float* al_kv = (float*)alloc(1536 * 4);
  float* be_kv = (float*)alloc(1536 * 4);
  float* al_q  = (float*)alloc(512 * 4);
  float* be_q  = (float*)alloc(512 * 4);
  float* al_p  = (float*)alloc(384 * 4);
  float* be_p  = (float*)alloc(384 * 4);
  u16* k_buf   = (u16*)alloc((size_t)32 * 8 * 1280 * 64 * 2);
  u16* vt_buf  = (u16*)alloc((size_t)32 * 8 * 128 * 1280 * 2);
  u16* q_buf   = (u16*)alloc((size_t)32 * 8 * 320 * 64 * 2);
  u16* bias_bf = (u16*)alloc((size_t)8 * 320 * 1280 * 2);
  u16* o_buf   = (u16*)alloc((size_t)32 * 320 * 1024 * 2);
  (void)ws_size; (void)n_in; (void)out_size;

  cvt_f32_bf16<<<(2621440 + 255) / 256, 256, 0, stream>>>(x, x_bf, 2621440);
  cvt_f32_bf16<<<(98304 + 255) / 256, 256, 0, stream>>>(W_kv, wkv_bf, 98304);
  cvt_f32_bf16<<<(32768 + 255) / 256, 256, 0, stream>>>(W_q, wq_bf, 32768);
  cvt_f32_bf16<<<(98304 + 255) / 256, 256, 0, stream>>>(W_p, wp_bf, 98304);
  bn_prep<<<6, 256, 0, stream>>>(g_kv, b_kv, rm_kv, rv_kv, al_kv, be_kv, 1536, 1.0f);
  bn_prep<<<2, 256, 0, stream>>>(g_q, b_q, rm_q, rv_q, al_q, be_q, 512, 0.125f);
  bn_prep<<<2, 256, 0, stream>>>(g_p, b_p, rm_p, rv_p, al_p, be_p, 384, 1.0f);
  bias_expand_bf16<<<(3276800 + 255) / 256, 256, 0, stream>>>(attn_bias, bias_idxs, bias_bf, n_off);

  gemm_kv<<<dim3(320, 12), 256, 0, stream>>>(x_bf, wkv_bf, al_kv, be_kv, k_buf, vt_buf);
  gemm_q<<<dim3(80, 4), 256, 0, stream>>>(x_bf, wq_bf, al_q, be_q, q_buf);
  attn_kernel<<<dim3(5, 8, 32), 256, 0, stream>>>(q_buf, k_buf, vt_buf, bias_bf, o_buf);
  gemm_p<<<dim3(80, 3), 256, 0, stream>>>(o_buf, wp_bf, al_p, be_p, (float*)d_out);
}

// Round 4
// 234.457 us; speedup vs baseline: 1.9504x; 1.9504x over previous
//
#include <hip/hip_runtime.h>
#include <hip/hip_bf16.h>
#include <cstdint>
#include <cstddef>

typedef unsigned short u16;
typedef __bf16 bf16x8 __attribute__((ext_vector_type(8)));
typedef float  f32x4  __attribute__((ext_vector_type(4)));
typedef u16    u16x8  __attribute__((ext_vector_type(8)));
typedef u16    u16x4  __attribute__((ext_vector_type(4)));

#define MFMA16(A_, B_, C_) __builtin_amdgcn_mfma_f32_16x16x32_bf16((A_), (B_), (C_), 0, 0, 0)

__device__ __forceinline__ u16 f2bf(float f) {
  return __builtin_bit_cast(u16, (__bf16)f);
}
__device__ __forceinline__ float bf2f(u16 v) {
  return (float)__builtin_bit_cast(__bf16, v);
}

// async global->LDS, 16B per lane. lds must be wave-uniform base; HW adds lane*16.
__device__ __forceinline__ void async16(u16* lds, const u16* g) {
  __builtin_amdgcn_global_load_lds(
      (const __attribute__((address_space(1))) unsigned int*)g,
      (__attribute__((address_space(3))) unsigned int*)lds, 16, 0, 0);
}

// ---------------- prep kernels ----------------

__global__ void cvt_f32_bf16(const float* __restrict__ src, u16* __restrict__ dst, int n4) {
  int i = blockIdx.x * 256 + threadIdx.x;
  if (i < n4) {
    const float4 v = ((const float4*)src)[i];
    u16x4 o;
    o[0] = f2bf(v.x); o[1] = f2bf(v.y); o[2] = f2bf(v.z); o[3] = f2bf(v.w);
    ((u16x4*)dst)[i] = o;
  }
}

__global__ void bn_prep(const float* __restrict__ g, const float* __restrict__ b,
                        const float* __restrict__ rm, const float* __restrict__ rv,
                        float* __restrict__ alpha, float* __restrict__ beta,
                        int n, float scale) {
  int i = blockIdx.x * 256 + threadIdx.x;
  if (i < n) {
    float a0 = g[i] * rsqrtf(rv[i] + 1e-5f);
    alpha[i] = a0 * scale;
    beta[i]  = (b[i] - rm[i] * a0) * scale;
  }
}

__global__ void bias_expand_bf16(const float* __restrict__ attn_bias, const int* __restrict__ idxs,
                                 u16* __restrict__ bias_bf, int n_off) {
  int i = blockIdx.x * 256 + threadIdx.x;
  if (i < 8 * 320 * 1280) {
    int h = i / (320 * 1280);
    int r = i - h * (320 * 1280);
    bias_bf[i] = f2bf(attn_bias[h * n_off + idxs[r]]);
  }
}

// ---------------- GEMM 1: kv = x @ W_kv^T, BN, scatter to K / V^T ----------------
// 128x128 tile, BK=64, 4 waves. Linear LDS [128][64] + global_load_lds width-16.

__global__ __launch_bounds__(256) void gemm_kv(
    const u16* __restrict__ A, const u16* __restrict__ Wt,
    const float* __restrict__ alpha, const float* __restrict__ beta,
    u16* __restrict__ k_buf, u16* __restrict__ vt_buf) {
  __shared__ __align__(16) u16 As[128 * 64];
  __shared__ __align__(16) u16 Bs[128 * 64];
  const int tid  = threadIdx.x;
  const int lane = tid & 63;
  const int w    = tid >> 6;
  const int wr   = (w >> 1) * 64, wc = (w & 1) * 64;
  const int lr   = lane >> 4, lc = lane & 15;
  const int m0   = blockIdx.x * 128;
  const int n0   = blockIdx.y * 128;
  const int scol  = (lane & 7) * 8;
  f32x4 acc[4][4] = {};

  for (int kt = 0; kt < 256; kt += 64) {
    if (kt) __syncthreads();
#pragma unroll
    for (int i = 0; i < 4; ++i) {
      const int row = w * 32 + i * 8 + (lane >> 3);
      async16(&As[(w * 32 + i * 8) * 64], A  + (size_t)(m0 + row) * 256 + kt + scol);
      async16(&Bs[(w * 32 + i * 8) * 64], Wt + (size_t)(n0 + row) * 256 + kt + scol);
    }
    __syncthreads();
#pragma unroll
    for (int kk = 0; kk < 2; ++kk) {
      bf16x8 af[4], bff[4];
#pragma unroll
      for (int m = 0; m < 4; ++m)
        af[m] = *(const bf16x8*)(&As[(wr + m * 16 + lc) * 64 + kk * 32 + lr * 8]);
#pragma unroll
      for (int n = 0; n < 4; ++n)
        bff[n] = *(const bf16x8*)(&Bs[(wc + n * 16 + lc) * 64 + kk * 32 + lr * 8]);
#pragma unroll
      for (int m = 0; m < 4; ++m)
#pragma unroll
        for (int n = 0; n < 4; ++n)
          acc[m][n] = MFMA16(af[m], bff[n], acc[m][n]);
    }
  }

  const int jr = lr * 4;
#pragma unroll
  for (int m = 0; m < 4; ++m) {
    const int r0  = m0 + wr + m * 16 + jr;
    const int b   = r0 / 1280;
    const int np0 = r0 - b * 1280;
#pragma unroll
    for (int n = 0; n < 4; ++n) {
      const int c    = n0 + wc + n * 16 + lc;
      const float al = alpha[c], be = beta[c];
      const int head = c / 192;
      const int off  = c - head * 192;
      const size_t bh = (size_t)(b * 8 + head);
      if (off < 64) {
#pragma unroll
        for (int j = 0; j < 4; ++j)
          k_buf[(bh * 1280 + np0 + j) * 64 + off] = f2bf(acc[m][n][j] * al + be);
      } else {
        u16x4 pk;
#pragma unroll
        for (int j = 0; j < 4; ++j) pk[j] = f2bf(acc[m][n][j] * al + be);
        *(u16x4*)(&vt_buf[(bh * 128 + (off - 64)) * 1280 + np0]) = pk;
      }
    }
  }
}

// ---------------- GEMM 2: q = subsample(x) @ W_q^T, BN, *0.125 (folded) ----------------

__device__ __forceinline__ int sub_src_row(int qr) {
  if (qr < 256) return ((qr >> 4) * 64) + ((qr & 15) * 2);
  int rr = qr - 256;
  return 1024 + ((rr >> 3) * 32) + ((rr & 7) * 2);
}

__global__ __launch_bounds__(256) void gemm_q(
    const u16* __restrict__ X, const u16* __restrict__ Wt,
    const float* __restrict__ alpha, const float* __restrict__ beta,
    u16* __restrict__ q_buf) {
  __shared__ __align__(16) u16 As[128 * 64];
  __shared__ __align__(16) u16 Bs[128 * 64];
  const int tid  = threadIdx.x;
  const int lane = tid & 63;
  const int w    = tid >> 6;
  const int wr   = (w >> 1) * 64, wc = (w & 1) * 64;
  const int lr   = lane >> 4, lc = lane & 15;
  const int m0   = blockIdx.x * 128;
  const int n0   = blockIdx.y * 128;
  const int scol  = (lane & 7) * 8;
  f32x4 acc[4][4] = {};

  for (int kt = 0; kt < 256; kt += 64) {
    if (kt) __syncthreads();
#pragma unroll
    for (int i = 0; i < 4; ++i) {
      const int row = w * 32 + i * 8 + (lane >> 3);
      const int gr  = m0 + row;
      const int bb  = gr / 320;
      const int qr  = gr - bb * 320;
      async16(&As[(w * 32 + i * 8) * 64],
              X + (size_t)(bb * 1280 + sub_src_row(qr)) * 256 + kt + scol);
      async16(&Bs[(w * 32 + i * 8) * 64], Wt + (size_t)(n0 + row) * 256 + kt + scol);
    }
    __syncthreads();
#pragma unroll
    for (int kk = 0; kk < 2; ++kk) {
      bf16x8 af[4], bff[4];
#pragma unroll
      for (int m = 0; m < 4; ++m)
        af[m] = *(const bf16x8*)(&As[(wr + m * 16 + lc) * 64 + kk * 32 + lr * 8]);
#pragma unroll
      for (int n = 0; n < 4; ++n)
        bff[n] = *(const bf16x8*)(&Bs[(wc + n * 16 + lc) * 64 + kk * 32 + lr * 8]);
#pragma unroll
      for (int m = 0; m < 4; ++m)
#pragma unroll
        for (int n = 0; n < 4; ++n)
          acc[m][n] = MFMA16(af[m], bff[n], acc[m][n]);
    }
  }

  const int jr = lr * 4;
#pragma unroll
  for (int m = 0; m < 4; ++m) {
#pragma unroll
    for (int n = 0; n < 4; ++n) {
      const int c    = n0 + wc + n * 16 + lc;   // < 512
      const float al = alpha[c], be = beta[c];
      const int head = c >> 6, kd = c & 63;
#pragma unroll
      for (int j = 0; j < 4; ++j) {
        const int r  = m0 + wr + m * 16 + jr + j;
        const int b  = r / 320;
        const int qr = r - b * 320;
        q_buf[((size_t)(b * 8 + head) * 320 + qr) * 64 + kd] = f2bf(acc[m][n][j] * al + be);
      }
    }
  }
}

// ---------------- attention ----------------
// 1 block = 64 q-rows (4 waves x 16), grid 1280 blocks (R1's winning shape).
// K/V reg-staged into XOR-swizzled LDS (T2: 2-way read conflicts, free).
// T14: global loads for tile t+1 issued under tile t's compute (dbl bias regs).
// Defer-max (THR=8): zero-shuffle fast path. Row-sum via all-ones MFMA column.

__global__ __launch_bounds__(256) void attn_kernel(
    const u16* __restrict__ q_buf, const u16* __restrict__ k_buf,
    const u16* __restrict__ vt_buf, const u16* __restrict__ bias_bf,
    u16* __restrict__ o_buf) {
  __shared__ __align__(16) u16 Ks[64 * 64];    // [key][kd], swizzled
  __shared__ __align__(16) u16 Vs[128 * 64];   // [d][k-in-tile], swizzled
  __shared__ __align__(16) u16 Ps[4 * 16 * 64]; // per-wave [q][k], swizzled
  const int tid  = threadIdx.x;
  const int lane = tid & 63;
  const int w    = tid >> 6;
  const int lr   = lane >> 4, lc = lane & 15, jr = lr * 4;
  const int h = blockIdx.y, b = blockIdx.z;
  const size_t bh = (size_t)(b * 8 + h);
  const int q0 = blockIdx.x * 64 + w * 16;
  const int swzk = (lc & 7) << 4;   // row-dependent XOR for frag reads (row&7 == lc&7)

  bf16x8 aq0, aq1;
  {
    const u16* qp = q_buf + (bh * 320 + q0 + lc) * 64 + lr * 8;
    aq0 = *(const bf16x8*)(qp);
    aq1 = *(const bf16x8*)(qp + 32);
  }
  bf16x8 ones;
#pragma unroll
  for (int i = 0; i < 8; ++i) ones[i] = (__bf16)1.0f;

  f32x4 oacc[8] = {};
  f32x4 lacc = {};
  float mrun[4] = {-3e38f, -3e38f, -3e38f, -3e38f};

  u16* Pw = &Ps[w * 16 * 64];
  const u16* bias_row = bias_bf + ((size_t)h * 320 + q0 + jr) * 1280;

  // staging registers (tile t+1 in flight during compute of t)
  u16x8 kreg[2], vreg[4];
  u16 bbA[16], bbB[16];
  const int srow = tid >> 3, sch = tid & 7;

  auto gkv = [&](int kt) {
    const u16* kg = k_buf + bh * 81920 + (size_t)(kt * 64 + srow) * 64 + sch * 8;
    kreg[0] = *(const u16x8*)(kg);
    kreg[1] = *(const u16x8*)(kg + 32 * 64);
    const u16* vg = vt_buf + bh * 163840 + (size_t)srow * 1280 + kt * 64 + sch * 8;
#pragma unroll
    for (int i = 0; i < 4; ++i) vreg[i] = *(const u16x8*)(vg + (size_t)i * 32 * 1280);
  };
  auto gbias = [&](int kt, u16* dst) {
    const u16* bp = bias_row + (size_t)kt * 64 + lc;
#pragma unroll
    for (int n = 0; n < 4; ++n)
#pragma unroll
      for (int j = 0; j < 4; ++j)
        dst[n * 4 + j] = bp[(size_t)j * 1280 + n * 16];
  };
  auto swzw = [&](u16* base, int row, int c, u16x8 v) {
    *(u16x8*)((char*)base + row * 128 + ((c * 16) ^ ((row & 7) << 4))) = v;
  };

  auto step = [&](int kt, const u16* bb, u16* bbn) {
    __syncthreads();                       // prior tile's LDS reads complete
    swzw(Ks, srow, sch, kreg[0]);
    swzw(Ks, srow + 32, sch, kreg[1]);
#pragma unroll
    for (int i = 0; i < 4; ++i) swzw(Vs, srow + i * 32, sch, vreg[i]);
    __syncthreads();
    const int ktn = (kt < 19) ? kt + 1 : 19;
    gkv(ktn);                              // fire next-tile loads (T14)
    gbias(ktn, bbn);

    // S = Q K^T + bias
    float pv[4][4];
    __builtin_amdgcn_s_setprio(1);
#pragma unroll
    for (int n = 0; n < 4; ++n) {
      const char* kp = (const char*)&Ks[(n * 16 + lc) * 64];
      f32x4 t = {};
      t = MFMA16(aq0, *(const bf16x8*)(kp + ((lr * 16) ^ swzk)), t);
      t = MFMA16(aq1, *(const bf16x8*)(kp + ((64 + lr * 16) ^ swzk)), t);
#pragma unroll
      for (int j = 0; j < 4; ++j) pv[n][j] = t[j] + bf2f(bb[n * 4 + j]);
    }
    __builtin_amdgcn_s_setprio(0);

    float mxl[4];
#pragma unroll
    for (int j = 0; j < 4; ++j)
      mxl[j] = fmaxf(fmaxf(pv[0][j], pv[1][j]), fmaxf(pv[2][j], pv[3][j]));

    int cond = 1;
#pragma unroll
    for (int j = 0; j < 4; ++j) cond &= (mxl[j] <= mrun[j] + 8.f);
    if (!__all(cond)) {
#pragma unroll
      for (int j = 0; j < 4; ++j) {
        float v = mxl[j];
        v = fmaxf(v, __shfl_xor(v, 1));
        v = fmaxf(v, __shfl_xor(v, 2));
        v = fmaxf(v, __shfl_xor(v, 4));
        v = fmaxf(v, __shfl_xor(v, 8));
        const float mnew = fmaxf(mrun[j], v);
        const float corr = __expf(mrun[j] - mnew);
        mrun[j] = mnew;
        lacc[j] *= corr;
#pragma unroll
        for (int nc = 0; nc < 8; ++nc) oacc[nc][j] *= corr;
      }
    }

    // P -> per-wave swizzled LDS (bf16), round-trip to A-fragment layout
#pragma unroll
    for (int n = 0; n < 4; ++n)
#pragma unroll
      for (int j = 0; j < 4; ++j) {
        const int row = jr + j;
        *(u16*)((char*)Pw + row * 128 + ((32 * n + 2 * lc) ^ ((row & 7) << 4))) =
            f2bf(__expf(pv[n][j] - mrun[j]));
      }
    asm volatile("" ::: "memory");  // order u16 LDS stores vs bf16x8 loads (TBAA guard)

    const char* pp = (const char*)&Pw[lc * 64];
    bf16x8 pa0 = *(const bf16x8*)(pp + ((lr * 16) ^ swzk));
    bf16x8 pa1 = *(const bf16x8*)(pp + ((64 + lr * 16) ^ swzk));
    __builtin_amdgcn_s_setprio(1);
    lacc = MFMA16(pa0, ones, lacc);  // row-sum: every lane gets l[row]
    lacc = MFMA16(pa1, ones, lacc);
#pragma unroll
    for (int nc = 0; nc < 8; ++nc) {
      const char* vp = (const char*)&Vs[(nc * 16 + lc) * 64];
      oacc[nc] = MFMA16(pa0, *(const bf16x8*)(vp + ((lr * 16) ^ swzk)), oacc[nc]);
      oacc[nc] = MFMA16(pa1, *(const bf16x8*)(vp + ((64 + lr * 16) ^ swzk)), oacc[nc]);
    }
    __builtin_amdgcn_s_setprio(0);
  };

  gkv(0);
  gbias(0, bbA);
#pragma unroll 1
  for (int kt = 0; kt < 20; kt += 2) {
    step(kt, bbA, bbB);
    step(kt + 1, bbB, bbA);
  }

  float invl[4];
#pragma unroll
  for (int j = 0; j < 4; ++j) invl[j] = 1.f / lacc[j];
#pragma unroll
  for (int nc = 0; nc < 8; ++nc) {
#pragma unroll
    for (int j = 0; j < 4; ++j) {
      const float xv = oacc[nc][j] * invl[j];
      const float hs = xv * fminf(fmaxf(xv + 3.f, 0.f), 6.f) * (1.f / 6.f);
      o_buf[((size_t)b * 320 + q0 + jr + j) * 1024 + h * 128 + nc * 16 + lc] = f2bf(hs);
    }
  }
}

// ---------------- GEMM 3: out = hswish(o) @ W_p^T, BN (f32 out) ----------------

__global__ __launch_bounds__(256) void gemm_p(
    const u16* __restrict__ O, const u16* __restrict__ Wt,
    const float* __restrict__ alpha, const float* __restrict__ beta,
    float* __restrict__ out) {
  __shared__ __align__(16) u16 As[128 * 64];
  __shared__ __align__(16) u16 Bs[128 * 64];
  const int tid  = threadIdx.x;
  const int lane = tid & 63;
  const int w    = tid >> 6;
  const int wr   = (w >> 1) * 64, wc = (w & 1) * 64;
  const int lr   = lane >> 4, lc = lane & 15;
  const int m0   = blockIdx.x * 128;
  const int n0   = blockIdx.y * 128;
  const int scol  = (lane & 7) * 8;
  f32x4 acc[4][4] = {};

  for (int kt = 0; kt < 1024; kt += 64) {
    if (kt) __syncthreads();
#pragma unroll
    for (int i = 0; i < 4; ++i) {
      const int row = w * 32 + i * 8 + (lane >> 3);
      async16(&As[(w * 32 + i * 8) * 64], O  + (size_t)(m0 + row) * 1024 + kt + scol);
      async16(&Bs[(w * 32 + i * 8) * 64], Wt + (size_t)(n0 + row) * 1024 + kt + scol);
    }
    __syncthreads();
#pragma unroll
    for (int kk = 0; kk < 2; ++kk) {
      bf16x8 af[4], bff[4];
#pragma unroll
      for (int m = 0; m < 4; ++m)
        af[m] = *(const bf16x8*)(&As[(wr + m * 16 + lc) * 64 + kk * 32 + lr * 8]);
#pragma unroll
      for (int n = 0; n < 4; ++n)
        bff[n] = *(const bf16x8*)(&Bs[(wc + n * 16 + lc) * 64 + kk * 32 + lr * 8]);
#pragma unroll
      for (int m = 0; m < 4; ++m)
#pragma unroll
        for (int n = 0; n < 4; ++n)
          acc[m][n] = MFMA16(af[m], bff[n], acc[m][n]);
    }
  }

  const int jr = lr * 4;
#pragma unroll
  for (int m = 0; m < 4; ++m) {
#pragma unroll
    for (int n = 0; n < 4; ++n) {
      const int c = n0 + wc + n * 16 + lc;   // < 384
      const float al = alpha[c], be = beta[c];
#pragma unroll
      for (int j = 0; j < 4; ++j) {
        const int r = m0 + wr + m * 16 + jr + j;
        out[(size_t)r * 384 + c] = acc[m][n][j] * al + be;
      }
    }
  }
}

// ---------------- launch ----------------

extern "C" void kernel_launch(void* const* d_in, const int* in_sizes, int n_in,
                              void* d_out, int out_size, void* d_ws, size_t ws_size,
                              hipStream_t stream) {
  const float* x      = (const float*)d_in[0];
  const float* W_kv   = (const float*)d_in[1];
  const float* g_kv   = (const float*)d_in[2];
  const float* b_kv   = (const float*)d_in[3];
  const float* rm_kv  = (const float*)d_in[4];
  const float* rv_kv  = (const float*)d_in[5];
  const float* W_q    = (const float*)d_in[6];
  const float* g_q    = (const float*)d_in[7];
  const float* b_q    = (const float*)d_in[8];
  const float* rm_q   = (const float*)d_in[9];
  const float* rv_q   = (const float*)d_in[10];
  const float* W_p    = (const float*)d_in[11];
  const float* g_p    = (const float*)d_in[12];
  const float* b_p    = (const float*)d_in[13];
  const float* rm_p   = (const float*)d_in[14];
  const float* rv_p   = (const float*)d_in[15];
  const float* attn_bias = (const float*)d_in[16];
  const int*   bias_idxs = (const int*)d_in[17];
  const int n_off = in_sizes[16] / 8;

  char* ws = (char*)d_ws;
  size_t off = 0;
  auto alloc = [&](size_t bytes) -> void* {
    void* p = ws + off;
    off += (bytes + 255) & ~(size_t)255;
    return p;
  };
  u16* x_bf    = (u16*)alloc((size_t)40960 * 256 * 2);
  u16* wkv_bf  = (u16*)alloc((size_t)1536 * 256 * 2);
  u16* wq_bf   = (u16*)alloc((size_t)512 * 256 * 2);
  u16* wp_bf   = (u16*)alloc((size_t)384 * 1024 * 2);
  float* al_kv = (float*)alloc(1536 * 4);
  float* be_kv = (float*)alloc(1536 * 4);
  float* al_q  = (float*)alloc(512 * 4);
  float* be_q  = (float*)alloc(512 * 4);
  float* al_p  = (float*)alloc(384 * 4);
  float* be_p  = (float*)alloc(384 * 4);
  u16* k_buf   = (u16*)alloc((size_t)32 * 8 * 1280 * 64 * 2);
  u16* vt_buf  = (u16*)alloc((size_t)32 * 8 * 128 * 1280 * 2);
  u16* q_buf   = (u16*)alloc((size_t)32 * 8 * 320 * 64 * 2);
  u16* bias_bf = (u16*)alloc((size_t)8 * 320 * 1280 * 2);
  u16* o_buf   = (u16*)alloc((size_t)32 * 320 * 1024 * 2);
  (void)ws_size; (void)n_in; (void)out_size;

  cvt_f32_bf16<<<(2621440 + 255) / 256, 256, 0, stream>>>(x, x_bf, 2621440);
  cvt_f32_bf16<<<(98304 + 255) / 256, 256, 0, stream>>>(W_kv, wkv_bf, 98304);
  cvt_f32_bf16<<<(32768 + 255) / 256, 256, 0, stream>>>(W_q, wq_bf, 32768);
  cvt_f32_bf16<<<(98304 + 255) / 256, 256, 0, stream>>>(W_p, wp_bf, 98304);
  bn_prep<<<6, 256, 0, stream>>>(g_kv, b_kv, rm_kv, rv_kv, al_kv, be_kv, 1536, 1.0f);
  bn_prep<<<2, 256, 0, stream>>>(g_q, b_q, rm_q, rv_q, al_q, be_q, 512, 0.125f);
  bn_prep<<<2, 256, 0, stream>>>(g_p, b_p, rm_p, rv_p, al_p, be_p, 384, 1.0f);
  bias_expand_bf16<<<(3276800 + 255) / 256, 256, 0, stream>>>(attn_bias, bias_idxs, bias_bf, n_off);

  gemm_kv<<<dim3(320, 12), 256, 0, stream>>>(x_bf, wkv_bf, al_kv, be_kv, k_buf, vt_buf);
  gemm_q<<<dim3(80, 4), 256, 0, stream>>>(x_bf, wq_bf, al_q, be_q, q_buf);
  attn_kernel<<<dim3(5, 8, 32), 256, 0, stream>>>(q_buf, k_buf, vt_buf, bias_bf, o_buf);
  gemm_p<<<dim3(80, 3), 256, 0, stream>>>(o_buf, wp_bf, al_p, be_p, (float*)d_out);
}